// Round 1
// baseline (430.368 us; speedup 1.0000x reference)
//
#include <hip/hip_runtime.h>

// Graph scatter-add: two etypes fused into one kernel.
//  buy:    new_item[dst] += h_user[src] * w_buy    (1M edges)
//  bought: new_user[dst] += h_item[src] * w_bought (1M edges)
// Mapping: one 64-lane wave per edge, lane = feature dim (D=64).
// Source-row read is a coalesced 256B segment; output via atomicAdd (f32,
// device scope, executes at L2).

#define DIM 64

__global__ void zero_f32(float4* __restrict__ out, long long n4) {
    long long i = (long long)blockIdx.x * blockDim.x + threadIdx.x;
    const long long stride = (long long)gridDim.x * blockDim.x;
    for (; i < n4; i += stride) out[i] = make_float4(0.f, 0.f, 0.f, 0.f);
}

__global__ void scatter_both(const float* __restrict__ h_user,
                             const float* __restrict__ h_item,
                             const int* __restrict__ buy_src,
                             const int* __restrict__ buy_dst,
                             const float* __restrict__ w_buy,
                             const int* __restrict__ bought_src,
                             const int* __restrict__ bought_dst,
                             const float* __restrict__ w_bought,
                             float* __restrict__ new_user,
                             float* __restrict__ new_item,
                             int n_buy, int n_total) {
    const int lane = threadIdx.x & 63;
    const int waves_per_block = blockDim.x >> 6;
    int wid = blockIdx.x * waves_per_block + (threadIdx.x >> 6);
    const int nwaves = gridDim.x * waves_per_block;

    for (int e = wid; e < n_total; e += nwaves) {
        const float* h;
        const int* srcp;
        const int* dstp;
        const float* wp;
        float* outp;
        int idx;
        if (e < n_buy) {
            h = h_user; srcp = buy_src; dstp = buy_dst; wp = w_buy;
            outp = new_item; idx = e;
        } else {
            h = h_item; srcp = bought_src; dstp = bought_dst; wp = w_bought;
            outp = new_user; idx = e - n_buy;
        }
        const int s = srcp[idx];
        const int d = dstp[idx];
        const float weight = wp[idx];
        const float v = h[(long long)s * DIM + lane] * weight;
        atomicAdd(outp + (long long)d * DIM + lane, v);
    }
}

extern "C" void kernel_launch(void* const* d_in, const int* in_sizes, int n_in,
                              void* d_out, int out_size, void* d_ws, size_t ws_size,
                              hipStream_t stream) {
    const float* h_user     = (const float*)d_in[0];
    const float* h_item     = (const float*)d_in[1];
    const int*   buy_src    = (const int*)d_in[2];
    const int*   buy_dst    = (const int*)d_in[3];
    const float* w_buy      = (const float*)d_in[4];
    const int*   bought_src = (const int*)d_in[5];
    const int*   bought_dst = (const int*)d_in[6];
    const float* w_bought   = (const float*)d_in[7];

    const int n_users  = in_sizes[0] / DIM;   // 100000
    const int n_buy    = in_sizes[2];         // 1000000
    const int n_bought = in_sizes[5];         // 1000000

    float* out      = (float*)d_out;
    float* new_user = out;                               // [n_users, 64]
    float* new_item = out + (long long)n_users * DIM;    // [n_items, 64]

    // 1) zero outputs (harness poisons d_out; we must produce exact sums)
    const long long n4 = (long long)out_size / 4;  // out_size divisible by 4
    zero_f32<<<2048, 256, 0, stream>>>((float4*)d_out, n4);

    // 2) fused scatter over both edge sets
    const int n_total = n_buy + n_bought;
    const int block = 256;                       // 4 waves/block
    const int grid  = 2048;                      // 8192 waves, ~244 edges each
    scatter_both<<<grid, block, 0, stream>>>(h_user, h_item,
                                             buy_src, buy_dst, w_buy,
                                             bought_src, bought_dst, w_bought,
                                             new_user, new_item,
                                             n_buy, n_total);
}

// Round 2
// 412.287 us; speedup vs baseline: 1.0439x; 1.0439x over previous
//
#include <hip/hip_runtime.h>

// Graph scatter-add via dst-binning (CSR-transpose built on device each call).
//  buy:    new_item[dst] += h_user[src] * w_buy    (1M edges)
//  bought: new_user[dst] += h_item[src] * w_bought (1M edges)
//
// R1 showed the atomic-per-lane version is atomic-throughput-bound
// (128M f32 atomics ~ 423us, WRITE_SIZE=500MB). Here we bin edges by dst
// (4M cheap u32 atomics total), then one wave per output row accumulates in
// registers and does ONE plain 256B store. Passes:
//   1. zero counters
//   2. histogram dst -> cnt
//   3. exclusive scan cnt -> off, cur (2 blocks, shuffle scan)
//   4. scatter {src,w} payloads to dst-sorted order (cur cursor atomics)
//   5. segment reduce: wave per row, gather h[src] (L3-resident), plain store

#define DIM 64

// ---------------- fallback path (R1) ----------------
__global__ void zero_f32(float4* __restrict__ out, long long n4) {
    long long i = (long long)blockIdx.x * blockDim.x + threadIdx.x;
    const long long stride = (long long)gridDim.x * blockDim.x;
    for (; i < n4; i += stride) out[i] = make_float4(0.f, 0.f, 0.f, 0.f);
}

__global__ void scatter_both(const float* __restrict__ h_user,
                             const float* __restrict__ h_item,
                             const int* __restrict__ buy_src,
                             const int* __restrict__ buy_dst,
                             const float* __restrict__ w_buy,
                             const int* __restrict__ bought_src,
                             const int* __restrict__ bought_dst,
                             const float* __restrict__ w_bought,
                             float* __restrict__ new_user,
                             float* __restrict__ new_item,
                             int n_buy, int n_total) {
    const int lane = threadIdx.x & 63;
    const int waves_per_block = blockDim.x >> 6;
    int wid = blockIdx.x * waves_per_block + (threadIdx.x >> 6);
    const int nwaves = gridDim.x * waves_per_block;
    for (int e = wid; e < n_total; e += nwaves) {
        const float* h; const int* srcp; const int* dstp; const float* wp;
        float* outp; int idx;
        if (e < n_buy) { h = h_user; srcp = buy_src; dstp = buy_dst; wp = w_buy; outp = new_item; idx = e; }
        else { h = h_item; srcp = bought_src; dstp = bought_dst; wp = w_bought; outp = new_user; idx = e - n_buy; }
        const int s = srcp[idx];
        const int d = dstp[idx];
        const float weight = wp[idx];
        const float v = h[(long long)s * DIM + lane] * weight;
        atomicAdd(outp + (long long)d * DIM + lane, v);
    }
}

// ---------------- binned path ----------------

__global__ void zero_u32(unsigned* __restrict__ p, int n) {
    int i = blockIdx.x * blockDim.x + threadIdx.x;
    const int stride = gridDim.x * blockDim.x;
    for (; i < n; i += stride) p[i] = 0u;
}

__global__ void hist_both(const int* __restrict__ buy_dst,
                          const int* __restrict__ bought_dst,
                          unsigned* __restrict__ cnt_item,
                          unsigned* __restrict__ cnt_user,
                          int n_buy, int n_total) {
    int i = blockIdx.x * blockDim.x + threadIdx.x;
    const int stride = gridDim.x * blockDim.x;
    for (; i < n_total; i += stride) {
        if (i < n_buy) atomicAdd(&cnt_item[buy_dst[i]], 1u);
        else           atomicAdd(&cnt_user[bought_dst[i - n_buy]], 1u);
    }
}

// Exclusive scan of cnt -> off, and off -> cur (cursor copy).
// Block 0 handles items, block 1 handles users. 1024 threads, 4 elems/thread.
__global__ __launch_bounds__(1024) void scan_two(
        const unsigned* __restrict__ cnt_item, unsigned* __restrict__ off_item,
        unsigned* __restrict__ cur_item, int n_item,
        const unsigned* __restrict__ cnt_user, unsigned* __restrict__ off_user,
        unsigned* __restrict__ cur_user, int n_user) {
    const unsigned* cnt; unsigned* off; unsigned* cur; int n;
    if (blockIdx.x == 0) { cnt = cnt_item; off = off_item; cur = cur_item; n = n_item; }
    else                 { cnt = cnt_user; off = off_user; cur = cur_user; n = n_user; }

    __shared__ unsigned wsum[16];
    const int lane = threadIdx.x & 63;
    const int wid  = threadIdx.x >> 6;
    unsigned carry = 0;

    for (int base = 0; base < n; base += 4096) {
        const int i0 = base + (int)threadIdx.x * 4;
        unsigned x0 = 0, x1 = 0, x2 = 0, x3 = 0;
        if (i0 + 3 < n) {
            uint4 v = *(const uint4*)(cnt + i0);
            x0 = v.x; x1 = v.y; x2 = v.z; x3 = v.w;
        } else {
            if (i0 + 0 < n) x0 = cnt[i0 + 0];
            if (i0 + 1 < n) x1 = cnt[i0 + 1];
            if (i0 + 2 < n) x2 = cnt[i0 + 2];
            if (i0 + 3 < n) x3 = cnt[i0 + 3];
        }
        const unsigned t0 = x0, t1 = t0 + x1, t2 = t1 + x2, t3 = t2 + x3;
        const unsigned thr_sum = t3;
        // wave-inclusive scan of per-thread sums
        unsigned sc = thr_sum;
        #pragma unroll
        for (int d = 1; d < 64; d <<= 1) {
            unsigned u = __shfl_up(sc, d, 64);
            if (lane >= d) sc += u;
        }
        if (lane == 63) wsum[wid] = sc;
        __syncthreads();
        if (wid == 0) {
            unsigned v = (lane < 16) ? wsum[lane] : 0u;
            #pragma unroll
            for (int d = 1; d < 16; d <<= 1) {
                unsigned u = __shfl_up(v, d, 64);
                if (lane >= d) v += u;
            }
            if (lane < 16) wsum[lane] = v;  // inclusive wave sums
        }
        __syncthreads();
        const unsigned wave_excl   = (wid == 0) ? 0u : wsum[wid - 1];
        const unsigned chunk_total = wsum[15];
        const unsigned thr_excl = carry + wave_excl + (sc - thr_sum);
        const unsigned e0 = thr_excl;
        const unsigned e1 = thr_excl + t0;
        const unsigned e2 = thr_excl + t1;
        const unsigned e3 = thr_excl + t2;
        if (i0 + 0 < n) { off[i0 + 0] = e0; cur[i0 + 0] = e0; }
        if (i0 + 1 < n) { off[i0 + 1] = e1; cur[i0 + 1] = e1; }
        if (i0 + 2 < n) { off[i0 + 2] = e2; cur[i0 + 2] = e2; }
        if (i0 + 3 < n) { off[i0 + 3] = e3; cur[i0 + 3] = e3; }
        __syncthreads();   // wsum reused next chunk
        carry += chunk_total;
    }
}

__global__ void scatter_payload(const int* __restrict__ buy_src,
                                const int* __restrict__ buy_dst,
                                const float* __restrict__ w_buy,
                                const int* __restrict__ bought_src,
                                const int* __restrict__ bought_dst,
                                const float* __restrict__ w_bought,
                                unsigned* __restrict__ cur_item,
                                unsigned* __restrict__ cur_user,
                                uint2* __restrict__ pay_buy,
                                uint2* __restrict__ pay_bought,
                                int n_buy, int n_total) {
    int i = blockIdx.x * blockDim.x + threadIdx.x;
    const int stride = gridDim.x * blockDim.x;
    for (; i < n_total; i += stride) {
        if (i < n_buy) {
            const int d = buy_dst[i];
            const unsigned pos = atomicAdd(&cur_item[d], 1u);
            pay_buy[pos] = make_uint2((unsigned)buy_src[i], __float_as_uint(w_buy[i]));
        } else {
            const int j = i - n_buy;
            const int d = bought_dst[j];
            const unsigned pos = atomicAdd(&cur_user[d], 1u);
            pay_bought[pos] = make_uint2((unsigned)bought_src[j], __float_as_uint(w_bought[j]));
        }
    }
}

// One wave per output row. rows [0, n_item) -> new_item, [n_item, ..) -> new_user.
__global__ void reduce_rows(const float* __restrict__ h_user,
                            const float* __restrict__ h_item,
                            const unsigned* __restrict__ off_item,
                            const unsigned* __restrict__ cur_item,
                            const unsigned* __restrict__ off_user,
                            const unsigned* __restrict__ cur_user,
                            const uint2* __restrict__ pay_buy,
                            const uint2* __restrict__ pay_bought,
                            float* __restrict__ new_user,
                            float* __restrict__ new_item,
                            int n_item, int n_rows) {
    const int lane = threadIdx.x & 63;
    const int row = blockIdx.x * (blockDim.x >> 6) + (threadIdx.x >> 6);
    if (row >= n_rows) return;

    const float* h; const unsigned* off; const unsigned* cur; const uint2* pay;
    float* outp; int r;
    if (row < n_item) { h = h_user; off = off_item; cur = cur_item; pay = pay_buy;    outp = new_item; r = row; }
    else              { h = h_item; off = off_user; cur = cur_user; pay = pay_bought; outp = new_user; r = row - n_item; }

    const unsigned start = off[r];
    const unsigned end   = cur[r];     // after scatter, cur[r] == off[r] + cnt[r]
    float acc = 0.f;
    unsigned k = start;
    for (; k + 4 <= end; k += 4) {
        const uint2 p0 = pay[k + 0];
        const uint2 p1 = pay[k + 1];
        const uint2 p2 = pay[k + 2];
        const uint2 p3 = pay[k + 3];
        acc += h[(size_t)p0.x * DIM + lane] * __uint_as_float(p0.y);
        acc += h[(size_t)p1.x * DIM + lane] * __uint_as_float(p1.y);
        acc += h[(size_t)p2.x * DIM + lane] * __uint_as_float(p2.y);
        acc += h[(size_t)p3.x * DIM + lane] * __uint_as_float(p3.y);
    }
    for (; k < end; ++k) {
        const uint2 p = pay[k];
        acc += h[(size_t)p.x * DIM + lane] * __uint_as_float(p.y);
    }
    outp[(size_t)r * DIM + lane] = acc;
}

extern "C" void kernel_launch(void* const* d_in, const int* in_sizes, int n_in,
                              void* d_out, int out_size, void* d_ws, size_t ws_size,
                              hipStream_t stream) {
    const float* h_user     = (const float*)d_in[0];
    const float* h_item     = (const float*)d_in[1];
    const int*   buy_src    = (const int*)d_in[2];
    const int*   buy_dst    = (const int*)d_in[3];
    const float* w_buy      = (const float*)d_in[4];
    const int*   bought_src = (const int*)d_in[5];
    const int*   bought_dst = (const int*)d_in[6];
    const float* w_bought   = (const float*)d_in[7];

    const int n_users  = in_sizes[0] / DIM;   // 100000
    const int n_items  = in_sizes[1] / DIM;   // 50000
    const int n_buy    = in_sizes[2];         // 1000000
    const int n_bought = in_sizes[5];         // 1000000
    const int n_total  = n_buy + n_bought;

    float* out      = (float*)d_out;
    float* new_user = out;                               // [n_users, 64]
    float* new_item = out + (long long)n_users * DIM;    // [n_items, 64]

    // carve workspace (256B-aligned arrays)
    char* w = (char*)d_ws;
    size_t used = 0;
    auto alloc = [&](size_t bytes) -> char* {
        char* p = w + used;
        used += (bytes + 255) & ~(size_t)255;
        return p;
    };
    unsigned* cnt_item = (unsigned*)alloc((size_t)n_items * 4);
    unsigned* off_item = (unsigned*)alloc((size_t)n_items * 4);
    unsigned* cur_item = (unsigned*)alloc((size_t)n_items * 4);
    unsigned* cnt_user = (unsigned*)alloc((size_t)n_users * 4);
    unsigned* off_user = (unsigned*)alloc((size_t)n_users * 4);
    unsigned* cur_user = (unsigned*)alloc((size_t)n_users * 4);
    uint2*    pay_buy    = (uint2*)alloc((size_t)n_buy * 8);
    uint2*    pay_bought = (uint2*)alloc((size_t)n_bought * 8);

    if (used > ws_size) {
        // fallback: R1 atomic path
        const long long n4 = (long long)out_size / 4;
        zero_f32<<<2048, 256, 0, stream>>>((float4*)d_out, n4);
        scatter_both<<<2048, 256, 0, stream>>>(h_user, h_item,
                                               buy_src, buy_dst, w_buy,
                                               bought_src, bought_dst, w_bought,
                                               new_user, new_item,
                                               n_buy, n_total);
        return;
    }

    // 1) zero counters
    const int n_cnt = n_items + n_users;   // cnt_item and cnt_user are adjacent-ish; zero separately
    zero_u32<<<(n_items + 255) / 256, 256, 0, stream>>>(cnt_item, n_items);
    zero_u32<<<(n_users + 255) / 256, 256, 0, stream>>>(cnt_user, n_users);
    (void)n_cnt;

    // 2) histogram
    hist_both<<<(n_total + 255) / 256, 256, 0, stream>>>(buy_dst, bought_dst,
                                                         cnt_item, cnt_user,
                                                         n_buy, n_total);

    // 3) scan (block 0: items, block 1: users)
    scan_two<<<2, 1024, 0, stream>>>(cnt_item, off_item, cur_item, n_items,
                                     cnt_user, off_user, cur_user, n_users);

    // 4) scatter payloads into dst-sorted order
    scatter_payload<<<(n_total + 255) / 256, 256, 0, stream>>>(
        buy_src, buy_dst, w_buy, bought_src, bought_dst, w_bought,
        cur_item, cur_user, pay_buy, pay_bought, n_buy, n_total);

    // 5) segment reduce: one wave per output row, plain store
    const int n_rows = n_items + n_users;
    const int waves_per_block = 4;  // 256 threads
    const int grid = (n_rows + waves_per_block - 1) / waves_per_block;
    reduce_rows<<<grid, 256, 0, stream>>>(h_user, h_item,
                                          off_item, cur_item, off_user, cur_user,
                                          pay_buy, pay_bought,
                                          new_user, new_item,
                                          n_items, n_rows);
}